// Round 9
// baseline (100.839 us; speedup 1.0000x reference)
//
#include <hip/hip_runtime.h>

#define NN 100000
#define DD 384
#define CC 8
#define ROWS 64

typedef unsigned int uint;
typedef _Float16 half8 __attribute__((ext_vector_type(8)));
typedef float floatx4 __attribute__((ext_vector_type(4)));

__device__ __forceinline__ constexpr int TIDX(int i, int j) { return i * (i + 1) / 2 + j; }

__device__ __forceinline__ uint pkh2(float a, float b) {
  return __builtin_bit_cast(uint, __builtin_amdgcn_cvt_pkrtz(a, b));
}

// B-fragment pre-pack. B[d][col]: col 0..35 = lower-tri of Sigmaw[d]+w w^T,
// col 36..43 = wbar[d][col-36], col 44..47 = 0.
// mfma_f32_16x16x32_f16 B-operand: lane holds 8 f16 at col = ct*16+(lane&15),
// k(j) = kt*32 + (lane>>4)*8 + j.  bfrag[(kt*3+ct)*64 + lane] = uint4.
__global__ __launch_bounds__(64) void vbpca_prep(
    const float* __restrict__ wbar, const float* __restrict__ Sigmaw,
    uint4* __restrict__ bfrag) {
  const int l = threadIdx.x;
  const int kt = blockIdx.x;  // 0..11
  const int kgrp = l >> 4;
#pragma unroll
  for (int ct = 0; ct < 3; ++ct) {
    const int col = ct * 16 + (l & 15);
    int ii = 0;
#pragma unroll
    for (int t = 0; t < 7; ++t) {
      if ((ii + 1) * (ii + 2) / 2 <= col && ii < 7) ++ii;
    }
    const int jj = col - ii * (ii + 1) / 2;
    float v[8];
#pragma unroll
    for (int j = 0; j < 8; ++j) {
      const int d = kt * 32 + kgrp * 8 + j;
      float val;
      if (col < 36) {
        val = Sigmaw[(size_t)d * 64 + ii * 8 + jj] + wbar[d * 8 + ii] * wbar[d * 8 + jj];
      } else if (col < 44) {
        val = wbar[d * 8 + (col - 36)];
      } else {
        val = 0.f;
      }
      v[j] = val;
    }
    uint4 u;
    u.x = pkh2(v[0], v[1]); u.y = pkh2(v[2], v[3]);
    u.z = pkh2(v[4], v[5]); u.w = pkh2(v[6], v[7]);
    bfrag[(kt * 3 + ct) * 64 + l] = u;
  }
}

// 256 threads = 4 waves; block owns 64 rows -> 128 interleaved A-rows
// (2r = O-mask, 2r+1 = O*(Y-mbar)). Double-buffered LDS tile (20-uint row
// stride: 2-way banks), 1 barrier/k-tile, depth-2 global prefetch.
// Epilogue: C-scatter via 49-pad LDS, Cholesky, coalesced staged writes.
__global__ __launch_bounds__(256, 5) void vbpca_main(
    const float* __restrict__ Y, const int* __restrict__ O,
    const uint4* __restrict__ bfrag, const float* __restrict__ mbar,
    const float* __restrict__ vyp, float* __restrict__ out) {
  __shared__ float smemf[6656];  // 26624 B
  float* mbar_l = smemf;                 // [384]
  uint* tile_l = (uint*)(smemf + 384);   // 2 x [128 rows][20] uints = 20480 B
  float* scat_l = smemf + 384;           // [128][49] overlay = 25088 B
  float* sigst = smemf + 384;            // [64][65] overlay (post-solve)
  float* xbst = smemf + 384 + 4160;      // [64][9]

  const int tid = threadIdx.x;
  const int l = tid & 63;
  const int w = tid >> 6;

  for (int i = tid; i < DD; i += 256) mbar_l[i] = mbar[i];

  const int lrow0 = tid >> 3;  // 0..31
  const int c4 = tid & 7;      // 0..7
  int rg0 = blockIdx.x * ROWS + lrow0;
  if (rg0 >= NN) rg0 = NN - 1;
  int rg1 = blockIdx.x * ROWS + lrow0 + 32;
  if (rg1 >= NN) rg1 = NN - 1;

  float4 yA0, yA1, yB0, yB1;
  int4 oA0, oA1, oB0, oB1;
#define ISSUE(S0y, S0o, S1y, S1o, KT)                                      \
  {                                                                        \
    const size_t off0 = (size_t)rg0 * DD + (KT) * 32 + c4 * 4;             \
    const size_t off1 = (size_t)rg1 * DD + (KT) * 32 + c4 * 4;             \
    S0y = *reinterpret_cast<const float4*>(Y + off0);                      \
    S0o = *reinterpret_cast<const int4*>(O + off0);                        \
    S1y = *reinterpret_cast<const float4*>(Y + off1);                      \
    S1o = *reinterpret_cast<const int4*>(O + off1);                        \
  }

#define PACK(S0y, S0o, S1y, S1o, KT, BUF)                                   \
  {                                                                         \
    const float4 mb = *reinterpret_cast<const float4*>(mbar_l + (KT)*32 + c4 * 4); \
    uint* tb = tile_l + (BUF)*2560;                                         \
    {                                                                       \
      const float f0 = (float)S0o.x, f1 = (float)S0o.y;                     \
      const float f2 = (float)S0o.z, f3 = (float)S0o.w;                     \
      uint* b0 = tb + (2 * lrow0) * 20 + c4 * 2;                            \
      b0[0] = pkh2(f0, f1); b0[1] = pkh2(f2, f3);                           \
      uint* b1 = tb + (2 * lrow0 + 1) * 20 + c4 * 2;                        \
      b1[0] = pkh2(f0 * (S0y.x - mb.x), f1 * (S0y.y - mb.y));               \
      b1[1] = pkh2(f2 * (S0y.z - mb.z), f3 * (S0y.w - mb.w));               \
    }                                                                       \
    {                                                                       \
      const float f0 = (float)S1o.x, f1 = (float)S1o.y;                     \
      const float f2 = (float)S1o.z, f3 = (float)S1o.w;                     \
      uint* b0 = tb + (2 * (lrow0 + 32)) * 20 + c4 * 2;                     \
      b0[0] = pkh2(f0, f1); b0[1] = pkh2(f2, f3);                           \
      uint* b1 = tb + (2 * (lrow0 + 32) + 1) * 20 + c4 * 2;                 \
      b1[0] = pkh2(f0 * (S1y.x - mb.x), f1 * (S1y.y - mb.y));               \
      b1[1] = pkh2(f2 * (S1y.z - mb.z), f3 * (S1y.w - mb.w));               \
    }                                                                       \
  }

  floatx4 acc[2][3];
#pragma unroll
  for (int i = 0; i < 2; ++i)
#pragma unroll
    for (int j = 0; j < 3; ++j) acc[i][j] = (floatx4){0.f, 0.f, 0.f, 0.f};

#define MFMA_PHASE(KT, BUF)                                                 \
  {                                                                         \
    const uint* tb = tile_l + (BUF)*2560;                                   \
    const half8 a0 = *reinterpret_cast<const half8*>(                       \
        tb + ((2 * w) * 16 + (l & 15)) * 20 + (l >> 4) * 4);                \
    const half8 a1 = *reinterpret_cast<const half8*>(                       \
        tb + ((2 * w + 1) * 16 + (l & 15)) * 20 + (l >> 4) * 4);            \
    const half8 b0 = __builtin_bit_cast(half8, bfrag[((KT)*3 + 0) * 64 + l]); \
    const half8 b1 = __builtin_bit_cast(half8, bfrag[((KT)*3 + 1) * 64 + l]); \
    const half8 b2 = __builtin_bit_cast(half8, bfrag[((KT)*3 + 2) * 64 + l]); \
    acc[0][0] = __builtin_amdgcn_mfma_f32_16x16x32_f16(a0, b0, acc[0][0], 0, 0, 0); \
    acc[0][1] = __builtin_amdgcn_mfma_f32_16x16x32_f16(a0, b1, acc[0][1], 0, 0, 0); \
    acc[0][2] = __builtin_amdgcn_mfma_f32_16x16x32_f16(a0, b2, acc[0][2], 0, 0, 0); \
    acc[1][0] = __builtin_amdgcn_mfma_f32_16x16x32_f16(a1, b0, acc[1][0], 0, 0, 0); \
    acc[1][1] = __builtin_amdgcn_mfma_f32_16x16x32_f16(a1, b1, acc[1][1], 0, 0, 0); \
    acc[1][2] = __builtin_amdgcn_mfma_f32_16x16x32_f16(a1, b2, acc[1][2], 0, 0, 0); \
  }

  ISSUE(yA0, oA0, yA1, oA1, 0);
  ISSUE(yB0, oB0, yB1, oB1, 1);
  __syncthreads();  // mbar ready

#pragma unroll 1
  for (int kt = 0; kt < 12; kt += 2) {
    PACK(yA0, oA0, yA1, oA1, kt, 0);
    if (kt + 2 < 12) ISSUE(yA0, oA0, yA1, oA1, kt + 2);
    __syncthreads();
    MFMA_PHASE(kt, 0);
    PACK(yB0, oB0, yB1, oB1, kt + 1, 1);
    if (kt + 3 < 12) ISSUE(yB0, oB0, yB1, oB1, kt + 3);
    __syncthreads();
    MFMA_PHASE(kt + 1, 1);
  }
  __syncthreads();  // all MFMA tile reads done before scat overwrite

  // ---- scatter C into LDS (C/D layout: col=l&15, row=(l>>4)*4+reg) ----
#pragma unroll
  for (int rtl = 0; rtl < 2; ++rtl) {
    const int rt = 2 * w + rtl;
#pragma unroll
    for (int ct = 0; ct < 3; ++ct) {
#pragma unroll
      for (int reg = 0; reg < 4; ++reg) {
        scat_l[(rt * 16 + (l >> 4) * 4 + reg) * 49 + ct * 16 + (l & 15)] =
            acc[rtl][ct][reg];
      }
    }
  }
  __syncthreads();

  float a[36], pr[CC];
  if (tid < 64) {
#pragma unroll
    for (int k = 0; k < 36; ++k) a[k] = scat_l[(2 * tid) * 49 + k];
#pragma unroll
    for (int j = 0; j < CC; ++j) pr[j] = scat_l[(2 * tid + 1) * 49 + 36 + j];
  }
  __syncthreads();  // scat reads complete before staging overwrite

  if (tid < 64) {
    const int row = tid;
    const float vy = *vyp;

    // ---- Cholesky solve: M = vy*I + A ----
    float L[36];
#pragma unroll
    for (int j = 0; j < CC; ++j) {
      float s = a[TIDX(j, j)] + vy;
#pragma unroll
      for (int k = 0; k < CC; ++k) {
        if (k < j) s -= L[TIDX(j, k)] * L[TIDX(j, k)];
      }
      const float dj = sqrtf(s);
      L[TIDX(j, j)] = dj;
      const float invdj = 1.0f / dj;
#pragma unroll
      for (int i = j + 1; i < CC; ++i) {
        float tt = a[TIDX(i, j)];
#pragma unroll
        for (int k = 0; k < CC; ++k) {
          if (k < j) tt -= L[TIDX(i, k)] * L[TIDX(j, k)];
        }
        L[TIDX(i, j)] = tt * invdj;
      }
    }

    float invd[CC];
#pragma unroll
    for (int i = 0; i < CC; ++i) invd[i] = 1.0f / L[TIDX(i, i)];
    float Li[36];
#pragma unroll
    for (int j = 0; j < CC; ++j) {
      Li[TIDX(j, j)] = invd[j];
#pragma unroll
      for (int i = j + 1; i < CC; ++i) {
        float s = 0.f;
#pragma unroll
        for (int k = 0; k < CC; ++k) {
          if (k >= j && k < i) s += L[TIDX(i, k)] * Li[TIDX(k, j)];
        }
        Li[TIDX(i, j)] = -s * invd[i];
      }
    }

    // sig (packed) and symmetric fill into staging; xb into staging.
    float sig[36];
#pragma unroll
    for (int i = 0; i < CC; ++i) {
#pragma unroll
      for (int j = 0; j <= i; ++j) {
        float s = 0.f;
#pragma unroll
        for (int k = 0; k < CC; ++k) {
          if (k >= i) s += Li[TIDX(k, i)] * Li[TIDX(k, j)];
        }
        sig[TIDX(i, j)] = vy * s;
      }
    }

    float uvec[CC];
#pragma unroll
    for (int i = 0; i < CC; ++i) {
      float s = 0.f;
#pragma unroll
      for (int j = 0; j < CC; ++j) {
        if (j <= i) s += Li[TIDX(i, j)] * pr[j];
      }
      uvec[i] = s;
    }
#pragma unroll
    for (int ll = 0; ll < CC; ++ll) {
      float s = 0.f;
#pragma unroll
      for (int i = 0; i < CC; ++i) {
        if (i >= ll) s += Li[TIDX(i, ll)] * uvec[i];
      }
      xbst[row * 9 + ll] = s;
    }
#pragma unroll
    for (int i = 0; i < CC; ++i) {
#pragma unroll
      for (int j = 0; j < CC; ++j) {
        sigst[row * 65 + i * 8 + j] = (j <= i) ? sig[TIDX(i, j)] : sig[TIDX(j, i)];
      }
    }
  }
  __syncthreads();

  // ---- coalesced copy-out ----
  const int valid = (NN - blockIdx.x * ROWS < ROWS) ? (NN - blockIdx.x * ROWS) : ROWS;
  float* __restrict__ sig_out = out + (size_t)NN * CC + (size_t)blockIdx.x * ROWS * 64;
  for (int f = tid; f < valid * 64; f += 256) {
    sig_out[f] = sigst[(f >> 6) * 65 + (f & 63)];
  }
  float* __restrict__ xb_out = out + (size_t)blockIdx.x * ROWS * CC;
  for (int f = tid; f < valid * 8; f += 256) {
    xb_out[f] = xbst[(f >> 3) * 9 + (f & 7)];
  }
}

extern "C" void kernel_launch(void* const* d_in, const int* in_sizes, int n_in,
                              void* d_out, int out_size, void* d_ws, size_t ws_size,
                              hipStream_t stream) {
  const float* Y = (const float*)d_in[0];
  const int* O = (const int*)d_in[1];
  const float* mbar = (const float*)d_in[2];
  const float* wbar = (const float*)d_in[3];
  const float* Sigmaw = (const float*)d_in[4];
  const float* vyp = (const float*)d_in[5];
  float* out = (float*)d_out;
  uint4* bfrag = (uint4*)d_ws;  // 12*3*64*16 = 36864 bytes

  vbpca_prep<<<12, 64, 0, stream>>>(wbar, Sigmaw, bfrag);
  vbpca_main<<<(NN + ROWS - 1) / ROWS, 256, 0, stream>>>(Y, O, bfrag, mbar, vyp, out);
}

// Round 10
// 82.357 us; speedup vs baseline: 1.2244x; 1.2244x over previous
//
#include <hip/hip_runtime.h>

#define NN 100000
#define DD 384
#define CC 8
#define ROWS 64      // orig rows per block
#define WROWS 16     // orig rows per wave
#define CROWS 8      // orig rows per chunk (16 A-rows = one M-tile)
#define TSTR 200     // uints per A-row in LDS tile (800 B, 16B-aligned)

typedef unsigned int uint;
typedef _Float16 half8 __attribute__((ext_vector_type(8)));
typedef float floatx4 __attribute__((ext_vector_type(4)));

__device__ __forceinline__ constexpr int TIDX(int i, int j) { return i * (i + 1) / 2 + j; }

__device__ __forceinline__ uint pkh2(float a, float b) {
  return __builtin_bit_cast(uint, __builtin_amdgcn_cvt_pkrtz(a, b));
}

// B-fragment pre-pack (unchanged, verified in R8/R9). B[d][col]:
// col 0..35 = lower-tri of Sigmaw[d]+w w^T, 36..43 = wbar, 44..47 = 0.
// mfma_f32_16x16x32_f16 B-operand: lane holds 8 f16 at col = ct*16+(lane&15),
// k(j) = kt*32 + (lane>>4)*8 + j.  bfrag[(kt*3+ct)*64 + lane] = uint4.
__global__ __launch_bounds__(64) void vbpca_prep(
    const float* __restrict__ wbar, const float* __restrict__ Sigmaw,
    uint4* __restrict__ bfrag) {
  const int l = threadIdx.x;
  const int kt = blockIdx.x;  // 0..11
  const int kgrp = l >> 4;
#pragma unroll
  for (int ct = 0; ct < 3; ++ct) {
    const int col = ct * 16 + (l & 15);
    int ii = 0;
#pragma unroll
    for (int t = 0; t < 7; ++t) {
      if ((ii + 1) * (ii + 2) / 2 <= col && ii < 7) ++ii;
    }
    const int jj = col - ii * (ii + 1) / 2;
    float v[8];
#pragma unroll
    for (int j = 0; j < 8; ++j) {
      const int d = kt * 32 + kgrp * 8 + j;
      float val;
      if (col < 36) {
        val = Sigmaw[(size_t)d * 64 + ii * 8 + jj] + wbar[d * 8 + ii] * wbar[d * 8 + jj];
      } else if (col < 44) {
        val = wbar[d * 8 + (col - 36)];
      } else {
        val = 0.f;
      }
      v[j] = val;
    }
    uint4 u;
    u.x = pkh2(v[0], v[1]); u.y = pkh2(v[2], v[3]);
    u.z = pkh2(v[4], v[5]); u.w = pkh2(v[6], v[7]);
    bfrag[(kt * 3 + ct) * 64 + l] = u;
  }
}

// 4 waves/block; wave owns 16 rows (2 chunks x 8 rows). Per chunk: stream
// 12KB Y + 12KB O as consecutive 1KB/instr loads, pack f16 (o,t) rows into a
// WAVE-PRIVATE LDS tile, then 12 k-tiles x 3 MFMAs (B-frags prefetched from
// L2). No barriers in main loop. Epilogue: scat -> Cholesky -> coalesced out.
__global__ __launch_bounds__(256, 3) void vbpca_main(
    const float* __restrict__ Y, const int* __restrict__ O,
    const uint4* __restrict__ bfrag, const float* __restrict__ mbar,
    const float* __restrict__ vyp, float* __restrict__ out) {
  __shared__ uint smem[13184];  // 52736 B -> 3 blocks/CU
  float* mbar_l = (float*)smem;              // [384]
  uint* tile = smem + 384;                   // [4 waves][16][TSTR]
  float* scat_l = (float*)(smem + 384);      // [128][49] overlay
  float* sigst = (float*)(smem + 384);       // [64][65] overlay
  float* xbst = (float*)(smem + 384) + 4160; // [64][9]

  const int tid = threadIdx.x;
  const int wu = __builtin_amdgcn_readfirstlane((int)(tid >> 6));
  const int l = tid & 63;

  for (int i = tid; i < DD; i += 256) mbar_l[i] = mbar[i];
  __syncthreads();  // mbar ready (only barrier before epilogue)

  uint* wtile = tile + wu * (16 * TSTR);
  const int r0c0 = blockIdx.x * ROWS + wu * WROWS;
  const int r0c1 = r0c0 + CROWS;

  float4 yv[2][3];
  int4 ov[2][3];

  // Stage S (0..3) of chunk with base row R0: 3 consecutive-1KB loads.
#define LOADSTG(B, S, R0)                                                   \
  {                                                                         \
    _Pragma("unroll") for (int j = 0; j < 3; ++j) {                         \
      const int f4 = (S)*192 + j * 64 + l; /* 0..767 float4 within chunk */ \
      const int i = f4 / 96;                                                \
      const int c96 = f4 - i * 96;                                          \
      int row = (R0) + i;                                                   \
      row = row < NN ? row : NN - 1;                                        \
      const size_t off = (size_t)row * 96 + c96;                            \
      yv[B][j] = reinterpret_cast<const float4*>(Y)[off];                   \
      ov[B][j] = reinterpret_cast<const int4*>(O)[off];                     \
    }                                                                       \
  }

#define PACKSTG(B, S)                                                       \
  {                                                                         \
    _Pragma("unroll") for (int j = 0; j < 3; ++j) {                         \
      const int f4 = (S)*192 + j * 64 + l;                                  \
      const int i = f4 / 96;                                                \
      const int c96 = f4 - i * 96;                                          \
      const float4 mb = *reinterpret_cast<const float4*>(mbar_l + c96 * 4); \
      const float4 y = yv[B][j];                                            \
      const int4 o = ov[B][j];                                              \
      const float f0 = (float)o.x, f1 = (float)o.y;                         \
      const float f2 = (float)o.z, f3 = (float)o.w;                         \
      uint* po = wtile + (2 * i) * TSTR + c96 * 2;                          \
      *reinterpret_cast<uint2*>(po) = make_uint2(pkh2(f0, f1), pkh2(f2, f3)); \
      uint* pt = wtile + (2 * i + 1) * TSTR + c96 * 2;                      \
      *reinterpret_cast<uint2*>(pt) =                                       \
          make_uint2(pkh2(f0 * (y.x - mb.x), f1 * (y.y - mb.y)),            \
                     pkh2(f2 * (y.z - mb.z), f3 * (y.w - mb.w)));           \
    }                                                                       \
  }

  floatx4 accA[3], accB[3];
#pragma unroll
  for (int j = 0; j < 3; ++j) {
    accA[j] = (floatx4){0.f, 0.f, 0.f, 0.f};
    accB[j] = (floatx4){0.f, 0.f, 0.f, 0.f};
  }

#define MFMA_LOOP(ACC)                                                      \
  {                                                                         \
    uint4 bf0 = bfrag[0 * 64 + l];                                          \
    uint4 bf1 = bfrag[1 * 64 + l];                                          \
    uint4 bf2 = bfrag[2 * 64 + l];                                          \
    _Pragma("unroll") for (int kt = 0; kt < 12; ++kt) {                     \
      const half8 av = *reinterpret_cast<const half8*>(                     \
          wtile + (l & 15) * TSTR + kt * 16 + (l >> 4) * 4);                \
      uint4 nb0, nb1, nb2;                                                  \
      if (kt < 11) {                                                        \
        nb0 = bfrag[((kt + 1) * 3 + 0) * 64 + l];                           \
        nb1 = bfrag[((kt + 1) * 3 + 1) * 64 + l];                           \
        nb2 = bfrag[((kt + 1) * 3 + 2) * 64 + l];                           \
      }                                                                     \
      ACC[0] = __builtin_amdgcn_mfma_f32_16x16x32_f16(                      \
          av, __builtin_bit_cast(half8, bf0), ACC[0], 0, 0, 0);             \
      ACC[1] = __builtin_amdgcn_mfma_f32_16x16x32_f16(                      \
          av, __builtin_bit_cast(half8, bf1), ACC[1], 0, 0, 0);             \
      ACC[2] = __builtin_amdgcn_mfma_f32_16x16x32_f16(                      \
          av, __builtin_bit_cast(half8, bf2), ACC[2], 0, 0, 0);             \
      bf0 = nb0; bf1 = nb1; bf2 = nb2;                                      \
    }                                                                       \
  }

  // ---- chunk 0: load/pack pipeline, then MFMA (no barriers) ----
  LOADSTG(0, 0, r0c0);
  LOADSTG(1, 1, r0c0);
  PACKSTG(0, 0);
  LOADSTG(0, 2, r0c0);
  PACKSTG(1, 1);
  LOADSTG(1, 3, r0c0);
  PACKSTG(0, 2);
  PACKSTG(1, 3);
  // chunk 1 streaming starts now, in flight under chunk 0's MFMAs
  LOADSTG(0, 0, r0c1);
  LOADSTG(1, 1, r0c1);
  MFMA_LOOP(accA);

  // ---- chunk 1 (tile reuse: per-wave DS ordering makes WAR safe) ----
  PACKSTG(0, 0);
  LOADSTG(0, 2, r0c1);
  PACKSTG(1, 1);
  LOADSTG(1, 3, r0c1);
  PACKSTG(0, 2);
  PACKSTG(1, 3);
  MFMA_LOOP(accB);

  // ---- epilogue ----
  __syncthreads();  // all waves done with tiles; scat overlays them

  // C/D layout: col = l&15, C-row m = (l>>4)*4 + reg; A-row-in-block =
  // wu*32 + chunk*16 + m; col ct*16+(l&15).
#pragma unroll
  for (int ct = 0; ct < 3; ++ct) {
#pragma unroll
    for (int reg = 0; reg < 4; ++reg) {
      const int m = (l >> 4) * 4 + reg;
      scat_l[(wu * 32 + m) * 49 + ct * 16 + (l & 15)] = accA[ct][reg];
      scat_l[(wu * 32 + 16 + m) * 49 + ct * 16 + (l & 15)] = accB[ct][reg];
    }
  }
  __syncthreads();

  float a[36], pr[CC];
  if (tid < 64) {
#pragma unroll
    for (int k = 0; k < 36; ++k) a[k] = scat_l[(2 * tid) * 49 + k];
#pragma unroll
    for (int j = 0; j < CC; ++j) pr[j] = scat_l[(2 * tid + 1) * 49 + 36 + j];
  }
  __syncthreads();  // scat reads complete before sigst overwrite

  if (tid < 64) {
    const int row = tid;
    const float vy = *vyp;

    float L[36];
#pragma unroll
    for (int j = 0; j < CC; ++j) {
      float s = a[TIDX(j, j)] + vy;
#pragma unroll
      for (int k = 0; k < CC; ++k) {
        if (k < j) s -= L[TIDX(j, k)] * L[TIDX(j, k)];
      }
      const float dj = sqrtf(s);
      L[TIDX(j, j)] = dj;
      const float invdj = 1.0f / dj;
#pragma unroll
      for (int i = j + 1; i < CC; ++i) {
        float tt = a[TIDX(i, j)];
#pragma unroll
        for (int k = 0; k < CC; ++k) {
          if (k < j) tt -= L[TIDX(i, k)] * L[TIDX(j, k)];
        }
        L[TIDX(i, j)] = tt * invdj;
      }
    }

    float invd[CC];
#pragma unroll
    for (int i = 0; i < CC; ++i) invd[i] = 1.0f / L[TIDX(i, i)];
    float Li[36];
#pragma unroll
    for (int j = 0; j < CC; ++j) {
      Li[TIDX(j, j)] = invd[j];
#pragma unroll
      for (int i = j + 1; i < CC; ++i) {
        float s = 0.f;
#pragma unroll
        for (int k = 0; k < CC; ++k) {
          if (k >= j && k < i) s += L[TIDX(i, k)] * Li[TIDX(k, j)];
        }
        Li[TIDX(i, j)] = -s * invd[i];
      }
    }

    float sig[36];
#pragma unroll
    for (int i = 0; i < CC; ++i) {
#pragma unroll
      for (int j = 0; j <= i; ++j) {
        float s = 0.f;
#pragma unroll
        for (int k = 0; k < CC; ++k) {
          if (k >= i) s += Li[TIDX(k, i)] * Li[TIDX(k, j)];
        }
        sig[TIDX(i, j)] = vy * s;
      }
    }

    float uvec[CC];
#pragma unroll
    for (int i = 0; i < CC; ++i) {
      float s = 0.f;
#pragma unroll
      for (int j = 0; j < CC; ++j) {
        if (j <= i) s += Li[TIDX(i, j)] * pr[j];
      }
      uvec[i] = s;
    }
#pragma unroll
    for (int ll = 0; ll < CC; ++ll) {
      float s = 0.f;
#pragma unroll
      for (int i = 0; i < CC; ++i) {
        if (i >= ll) s += Li[TIDX(i, ll)] * uvec[i];
      }
      xbst[row * 9 + ll] = s;
    }
#pragma unroll
    for (int i = 0; i < CC; ++i) {
#pragma unroll
      for (int j = 0; j < CC; ++j) {
        sigst[row * 65 + i * 8 + j] = (j <= i) ? sig[TIDX(i, j)] : sig[TIDX(j, i)];
      }
    }
  }
  __syncthreads();

  // ---- coalesced copy-out ----
  const int valid = (NN - blockIdx.x * ROWS < ROWS) ? (NN - blockIdx.x * ROWS) : ROWS;
  float* __restrict__ sig_out = out + (size_t)NN * CC + (size_t)blockIdx.x * ROWS * 64;
  for (int f = tid; f < valid * 64; f += 256) {
    sig_out[f] = sigst[(f >> 6) * 65 + (f & 63)];
  }
  float* __restrict__ xb_out = out + (size_t)blockIdx.x * ROWS * CC;
  for (int f = tid; f < valid * 8; f += 256) {
    xb_out[f] = xbst[(f >> 3) * 9 + (f & 7)];
  }
}

extern "C" void kernel_launch(void* const* d_in, const int* in_sizes, int n_in,
                              void* d_out, int out_size, void* d_ws, size_t ws_size,
                              hipStream_t stream) {
  const float* Y = (const float*)d_in[0];
  const int* O = (const int*)d_in[1];
  const float* mbar = (const float*)d_in[2];
  const float* wbar = (const float*)d_in[3];
  const float* Sigmaw = (const float*)d_in[4];
  const float* vyp = (const float*)d_in[5];
  float* out = (float*)d_out;
  uint4* bfrag = (uint4*)d_ws;  // 12*3*64*16 = 36864 bytes

  vbpca_prep<<<12, 64, 0, stream>>>(wbar, Sigmaw, bfrag);
  vbpca_main<<<(NN + ROWS - 1) / ROWS, 256, 0, stream>>>(Y, O, bfrag, mbar, vyp, out);
}